// Round 5
// baseline (421.759 us; speedup 1.0000x reference)
//
#include <hip/hip_runtime.h>
#include <hip/hip_bf16.h>

#define VN 50000
#define EN 800000
#define BN 4
#define CINN 64
#define COUTN 128
#define KN 4
#define FN 256  // BN * CINN

typedef __attribute__((ext_vector_type(8))) short short8;
typedef __attribute__((ext_vector_type(8))) unsigned short ushort8;
typedef __attribute__((ext_vector_type(4))) float floatx4;
typedef __attribute__((ext_vector_type(2))) float floatx2;

__device__ __forceinline__ float bf2f(unsigned short u) {
    union { unsigned int i; float f; } c;
    c.i = ((unsigned int)u) << 16;
    return c.f;
}
__device__ __forceinline__ unsigned short f2bf(float f) {
    __hip_bfloat16 h = __float2bfloat16(f);
    return *reinterpret_cast<unsigned short*>(&h);
}

#define RP_BLOCKS 196    // (VN+1+255)/256
#define WT_BLOCKS 128    // 128*256/256
#define EP_BLOCKS 3125   // EN/256
#define TP_BX 782        // (VN+63)/64
#define TP_BLOCKS (TP_BX * 4)

// ---------------------------------------------------------------------------
// Fused setup (unchanged, known-good): row_ptr lower_bound; wT transpose+bf16;
// packed (col,val) 8B edge records; 64x64 x-transpose fp32->bf16 into x0[v][256].
// ---------------------------------------------------------------------------
__global__ __launch_bounds__(256) void setup_fused(const int* __restrict__ rows,
                                                   int* __restrict__ row_ptr,
                                                   const float* __restrict__ w,
                                                   ushort* __restrict__ wT,
                                                   const float* __restrict__ x,
                                                   ushort* __restrict__ x0,
                                                   const int* __restrict__ cols,
                                                   const float* __restrict__ vals,
                                                   unsigned long long* __restrict__ epack) {
    __shared__ float tile[64][65];
    int blk = blockIdx.x;
    int tid = threadIdx.x;
    if (blk < RP_BLOCKS) {
        int v = blk * 256 + tid;
        if (v > VN) return;
        int lo = 0, hi = EN;
        while (lo < hi) {
            int mid = (lo + hi) >> 1;
            if (rows[mid] < v) lo = mid + 1; else hi = mid;
        }
        row_ptr[v] = lo;
        return;
    }
    if (blk < RP_BLOCKS + WT_BLOCKS) {
        int idx = (blk - RP_BLOCKS) * 256 + tid;  // 32768 total
        int o = idx >> 8;
        int kk = idx & 255;
        wT[idx] = f2bf(w[(size_t)kk * COUTN + o]);
        return;
    }
    if (blk < RP_BLOCKS + WT_BLOCKS + EP_BLOCKS) {
        int idx = (blk - RP_BLOCKS - WT_BLOCKS) * 256 + tid;  // 800000 total
        unsigned int c = (unsigned int)cols[idx];
        unsigned int wv = __float_as_uint(vals[idx]);
        epack[idx] = ((unsigned long long)wv << 32) | (unsigned long long)c;
        return;
    }
    int t = blk - RP_BLOCKS - WT_BLOCKS - EP_BLOCKS;
    int v0 = (t % TP_BX) * 64;
    int f0 = (t / TP_BX) * 64;
    int tx = tid & 63;
    int ty = tid >> 6;
#pragma unroll
    for (int r = 0; r < 16; ++r) {
        int f = f0 + ty + r * 4;
        int v = v0 + tx;
        if (v < VN) tile[ty + r * 4][tx] = x[(size_t)f * VN + v];
    }
    __syncthreads();
#pragma unroll
    for (int r = 0; r < 16; ++r) {
        int v = v0 + ty + r * 4;
        int f = f0 + tx;
        if (v < VN) x0[(size_t)v * FN + f] = f2bf(tile[tx][ty + r * 4]);
    }
}

// ---------------------------------------------------------------------------
// bf16 SpMM (round-0 structure, verified): out[v,:] = alpha*sum_e w_e*z[c_e,:]
// + beta*prev[v,:]. One wave per vertex; halves on even/odd edges; lane owns
// 8 features. Delta this round: float2-pair accumulation so the compiler can
// emit v_pk_fma_f32 (IEEE-identical f32 math, ~25% fewer VALU ops).
// ---------------------------------------------------------------------------
__global__ __launch_bounds__(256) void spmm_cheb_bf16(ushort* __restrict__ out,
                                                      const ushort* __restrict__ z,
                                                      const ushort* __restrict__ prev,
                                                      const int* __restrict__ row_ptr,
                                                      const unsigned long long* __restrict__ epack,
                                                      float alpha, float beta) {
    int row = (int)((blockIdx.x * blockDim.x + threadIdx.x) >> 6);
    int lane = threadIdx.x & 63;
    if (row >= VN) return;
    int e0 = row_ptr[row];
    int e1 = row_ptr[row + 1];
    int half = lane >> 5;        // 0: even edges, 1: odd edges
    int fl = (lane & 31) * 8;    // 8 features per lane

    floatx2 A0[4], A1[4];
#pragma unroll
    for (int p = 0; p < 4; ++p) { A0[p] = (floatx2){0.f, 0.f}; A1[p] = (floatx2){0.f, 0.f}; }

#define ZPAIR(zz, p) ((floatx2){bf2f((zz)[2*(p)]), bf2f((zz)[2*(p)+1])})

    int e = e0 + half;
    for (; e + 6 < e1; e += 8) {
        unsigned long long d0 = epack[e];
        unsigned long long d1 = epack[e + 2];
        unsigned long long d2 = epack[e + 4];
        unsigned long long d3 = epack[e + 6];
        ushort8 z0 = *reinterpret_cast<const ushort8*>(z + (size_t)(unsigned int)d0 * FN + fl);
        ushort8 z1 = *reinterpret_cast<const ushort8*>(z + (size_t)(unsigned int)d1 * FN + fl);
        ushort8 z2 = *reinterpret_cast<const ushort8*>(z + (size_t)(unsigned int)d2 * FN + fl);
        ushort8 z3 = *reinterpret_cast<const ushort8*>(z + (size_t)(unsigned int)d3 * FN + fl);
        float w0 = __uint_as_float((unsigned int)(d0 >> 32));
        float w1 = __uint_as_float((unsigned int)(d1 >> 32));
        float w2 = __uint_as_float((unsigned int)(d2 >> 32));
        float w3 = __uint_as_float((unsigned int)(d3 >> 32));
        floatx2 wv0 = (floatx2){w0, w0}, wv1 = (floatx2){w1, w1};
        floatx2 wv2 = (floatx2){w2, w2}, wv3 = (floatx2){w3, w3};
#pragma unroll
        for (int p = 0; p < 4; ++p) A0[p] += wv0 * ZPAIR(z0, p);
#pragma unroll
        for (int p = 0; p < 4; ++p) A1[p] += wv1 * ZPAIR(z1, p);
#pragma unroll
        for (int p = 0; p < 4; ++p) A0[p] += wv2 * ZPAIR(z2, p);
#pragma unroll
        for (int p = 0; p < 4; ++p) A1[p] += wv3 * ZPAIR(z3, p);
    }
    for (; e + 2 < e1; e += 4) {
        unsigned long long d0 = epack[e];
        unsigned long long d1 = epack[e + 2];
        ushort8 z0 = *reinterpret_cast<const ushort8*>(z + (size_t)(unsigned int)d0 * FN + fl);
        ushort8 z1 = *reinterpret_cast<const ushort8*>(z + (size_t)(unsigned int)d1 * FN + fl);
        float w0 = __uint_as_float((unsigned int)(d0 >> 32));
        float w1 = __uint_as_float((unsigned int)(d1 >> 32));
        floatx2 wv0 = (floatx2){w0, w0}, wv1 = (floatx2){w1, w1};
#pragma unroll
        for (int p = 0; p < 4; ++p) A0[p] += wv0 * ZPAIR(z0, p);
#pragma unroll
        for (int p = 0; p < 4; ++p) A1[p] += wv1 * ZPAIR(z1, p);
    }
    for (; e < e1; e += 2) {
        unsigned long long d0 = epack[e];
        ushort8 z0 = *reinterpret_cast<const ushort8*>(z + (size_t)(unsigned int)d0 * FN + fl);
        float w0 = __uint_as_float((unsigned int)(d0 >> 32));
        floatx2 wv0 = (floatx2){w0, w0};
#pragma unroll
        for (int p = 0; p < 4; ++p) A0[p] += wv0 * ZPAIR(z0, p);
    }
#undef ZPAIR

    float acc0[8];
#pragma unroll
    for (int p = 0; p < 4; ++p) {
        floatx2 m = A0[p] + A1[p];
        acc0[2 * p] = m[0];
        acc0[2 * p + 1] = m[1];
    }
    // butterfly: merge even/odd halves
#pragma unroll
    for (int j = 0; j < 8; ++j) acc0[j] += __shfl(acc0[j], lane ^ 32);

    if (half == 0) {
        ushort8 res;
        if (beta != 0.f) {
            ushort8 pv = *reinterpret_cast<const ushort8*>(prev + (size_t)row * FN + fl);
#pragma unroll
            for (int j = 0; j < 8; ++j)
                res[j] = f2bf(alpha * acc0[j] + beta * bf2f(pv[j]));
        } else {
#pragma unroll
            for (int j = 0; j < 8; ++j)
                res[j] = f2bf(alpha * acc0[j]);
        }
        *reinterpret_cast<ushort8*>(out + (size_t)row * FN + fl) = res;
    }
}

// ---------------------------------------------------------------------------
// MFMA GEMM v2:  out[b,o,v] = sum_k wT[o][k] * x(v)[k] + bias[o]
// OPERAND SWAP vs v1 (fragment indexing is symmetric, verified structure):
//   A = x-tile (M = v, 64/block), B = wT (N = o = 128).
//   C layout: row(quad*4+reg) = v, col(lane&15) = o  ->  each lane's 4 acc
//   regs are 4 CONSECUTIVE v  ->  float4 stores (8/thread vs 64 scalar).
// 64-wide v tiles: grid 782x4, LDS 24KB (lsX 8KB + lsW 16KB) -> 6 blocks/CU.
// T14 register prefetch: next kc's staging loads issued before the MFMA
// phase so global latency hides under compute.
// ---------------------------------------------------------------------------
__global__ __launch_bounds__(256, 4) void cheb_gemm_mfma(float* __restrict__ out,
                                                         const ushort* __restrict__ xbase,
                                                         const ushort* __restrict__ wT,
                                                         const float* __restrict__ bias) {
    __shared__ __align__(16) short lsX[64 * 64];    // 8KB: 64 v-rows x 64 k
    __shared__ __align__(16) short lsW[128 * 64];   // 16KB: 128 o-rows x 64 k

    int b = blockIdx.y;
    int v0 = blockIdx.x * 64;
    int tid = threadIdx.x;
    int lane = tid & 63;
    int w = tid >> 6;
    int wv = w & 1;              // v-half: 2 x 32 rows
    int wo = w >> 1;             // o-half: 2 x 64 cols
    int ln = lane & 15;
    int quad = lane >> 4;

    // W staging geometry: 2 threads per o-row, 4 x 16B each
    int srowW = tid >> 1;
    int posW0 = (tid & 1) * 4;
    // X staging geometry: 4 threads per v-row, 2 x 16B each
    int srowX = tid >> 2;
    int posX0 = (tid & 3) * 2;
    int vX = v0 + srowX;
    bool okX = (vX < VN);

    floatx4 acc[2][4];
#pragma unroll
    for (int mi = 0; mi < 2; ++mi)
#pragma unroll
        for (int ni = 0; ni < 4; ++ni) acc[mi][ni] = (floatx4){0.f, 0.f, 0.f, 0.f};

    uint4 pW[4], pX[2];

#define LOADW(KC)                                                                       \
    {                                                                                   \
        _Pragma("unroll")                                                               \
        for (int j = 0; j < 4; ++j) {                                                   \
            int g = (posW0 + j) ^ (srowW & 7);                                          \
            pW[j] = *reinterpret_cast<const uint4*>(wT + (size_t)srowW * 256 + (KC) * 64 + g * 8); \
        }                                                                               \
    }
#define LOADX(KC)                                                                       \
    {                                                                                   \
        const ushort* src = xbase + (size_t)(KC) * VN * FN + (size_t)vX * FN + b * CINN; \
        _Pragma("unroll")                                                               \
        for (int j = 0; j < 2; ++j) {                                                   \
            int g = (posX0 + j) ^ (srowX & 7);                                          \
            if (okX) pX[j] = *reinterpret_cast<const uint4*>(src + g * 8);              \
            else     pX[j] = make_uint4(0u, 0u, 0u, 0u);                                \
        }                                                                               \
    }

    LOADW(0);
    LOADX(0);

#pragma unroll
    for (int kc = 0; kc < 4; ++kc) {
        __syncthreads();   // previous phase's LDS reads complete
#pragma unroll
        for (int j = 0; j < 4; ++j)
            *reinterpret_cast<uint4*>(&lsW[(srowW * 8 + posW0 + j) * 8]) = pW[j];
#pragma unroll
        for (int j = 0; j < 2; ++j)
            *reinterpret_cast<uint4*>(&lsX[(srowX * 8 + posX0 + j) * 8]) = pX[j];
        __syncthreads();

        if (kc < 3) {      // prefetch next kc while this kc's MFMAs run
            LOADW(kc + 1);
            LOADX(kc + 1);
        }

#pragma unroll
        for (int s = 0; s < 2; ++s) {
            short8 afr[2], bfr[4];
#pragma unroll
            for (int mi = 0; mi < 2; ++mi) {
                int r = wv * 32 + mi * 16 + ln;           // v-row
                int pos = (s * 4 + quad) ^ (r & 7);
                afr[mi] = *reinterpret_cast<const short8*>(&lsX[(r * 8 + pos) * 8]);
            }
#pragma unroll
            for (int ni = 0; ni < 4; ++ni) {
                int r = wo * 64 + ni * 16 + ln;           // o-row
                int pos = (s * 4 + quad) ^ (r & 7);
                bfr[ni] = *reinterpret_cast<const short8*>(&lsW[(r * 8 + pos) * 8]);
            }
#pragma unroll
            for (int mi = 0; mi < 2; ++mi)
#pragma unroll
                for (int ni = 0; ni < 4; ++ni)
                    acc[mi][ni] = __builtin_amdgcn_mfma_f32_16x16x32_bf16(
                        afr[mi], bfr[ni], acc[mi][ni], 0, 0, 0);
        }
    }
#undef LOADW
#undef LOADX

    // epilogue: row(quad*4+r) = v -> float4 stores of 4 consecutive v
#pragma unroll
    for (int mi = 0; mi < 2; ++mi) {
        int vb = v0 + wv * 32 + mi * 16 + quad * 4;
#pragma unroll
        for (int ni = 0; ni < 4; ++ni) {
            int o = wo * 64 + ni * 16 + ln;
            float bv = bias[o];
            size_t obase = (size_t)(b * COUTN + o) * VN;
            floatx4 res = acc[mi][ni] + bv;
            if (vb + 3 < VN) {
                *reinterpret_cast<floatx4*>(out + obase + vb) = res;
            } else {
#pragma unroll
                for (int r = 0; r < 4; ++r)
                    if (vb + r < VN) out[obase + vb + r] = res[r];
            }
        }
    }
}

// ---------------------------------------------------------------------------
extern "C" void kernel_launch(void* const* d_in, const int* in_sizes, int n_in,
                              void* d_out, int out_size, void* d_ws, size_t ws_size,
                              hipStream_t stream) {
    const float* x        = (const float*)d_in[0];
    const int*   lap_rows = (const int*)d_in[1];
    const int*   lap_cols = (const int*)d_in[2];
    const float* lap_vals = (const float*)d_in[3];
    const float* weight   = (const float*)d_in[4];
    const float* bias     = (const float*)d_in[5];
    float* out = (float*)d_out;

    char* ws = (char*)d_ws;
    ushort* x0 = (ushort*)ws;                        // 4 x (V,256) bf16, contiguous
    ushort* x1 = x0 + (size_t)VN * FN;
    ushort* x2 = x1 + (size_t)VN * FN;
    ushort* x3 = x2 + (size_t)VN * FN;
    size_t xbytes = (size_t)4 * VN * FN * sizeof(ushort);
    int* row_ptr = (int*)(ws + xbytes);              // V+1 ints
    size_t rp_end = xbytes + (size_t)(VN + 1) * sizeof(int);
    rp_end = (rp_end + 15) & ~(size_t)15;            // 16B align
    ushort* wT = (ushort*)(ws + rp_end);             // (128,256) bf16 = 64KB
    size_t wt_end = rp_end + (size_t)COUTN * FN * sizeof(ushort);
    unsigned long long* epack = (unsigned long long*)(ws + wt_end);  // 6.4MB

    setup_fused<<<RP_BLOCKS + WT_BLOCKS + EP_BLOCKS + TP_BLOCKS, 256, 0, stream>>>(
        lap_rows, row_ptr, weight, wT, x, x0, lap_cols, lap_vals, epack);
    // x1 = L x0
    spmm_cheb_bf16<<<(VN + 3) / 4, 256, 0, stream>>>(x1, x0, x0, row_ptr, epack, 1.f, 0.f);
    // x2 = 2 L x1 - x0
    spmm_cheb_bf16<<<(VN + 3) / 4, 256, 0, stream>>>(x2, x1, x0, row_ptr, epack, 2.f, -1.f);
    // x3 = 2 L x2 - x1
    spmm_cheb_bf16<<<(VN + 3) / 4, 256, 0, stream>>>(x3, x2, x1, row_ptr, epack, 2.f, -1.f);
    // out = sum_k xk @ Wk + bias  (MFMA)
    cheb_gemm_mfma<<<dim3((VN + 63) / 64, BN), 256, 0, stream>>>(out, x0, wT, bias);
}